// Round 2
// baseline (941.674 us; speedup 1.0000x reference)
//
#include <hip/hip_runtime.h>
#include <hip/hip_bf16.h>
#include <stdint.h>

// ---------------------------------------------------------------------------
// Int8Linear: y = x @ Wq^T + b, Wq = dequant(int8-quant(W)) per-tensor absmax.
// R2: (a) lane-permuted global_load_lds staging so LDS holds tiles in MFMA
//     fragment order -> ds_read_b128 at base+16*lane, conflict-free.
//     (b) fuse x-cast into the absmax kernel (one fewer graph node).
// Workspace: [0..4) absmax bits | 256 + x_bf16 (64 MiB) | wq_bf16 (32 MiB)
// ---------------------------------------------------------------------------

typedef __attribute__((ext_vector_type(8))) short short8;   // 8 x bf16 (4 VGPRs)
typedef __attribute__((ext_vector_type(4))) float f32x4;    // MFMA accumulator

#define BM 128
#define BN 128
#define BK 32

// float -> bf16, round-to-nearest-even
__device__ __forceinline__ unsigned short f2bf(float f) {
    unsigned u = __float_as_uint(f);
    unsigned r = 0x7fffu + ((u >> 16) & 1u);
    return (unsigned short)((u + r) >> 16);
}

// ---------------- fused: absmax over W + cast x -> bf16 --------------------
__global__ void prep_kernel(const float* __restrict__ W,
                            const float* __restrict__ X,
                            unsigned short* __restrict__ Xb,
                            unsigned* __restrict__ amax,
                            int nw4, int nx4) {
    int i0 = blockIdx.x * blockDim.x + threadIdx.x;
    int stride = gridDim.x * blockDim.x;
    float m = 0.f;
    for (int idx = i0; idx < nw4; idx += stride) {
        float4 v = ((const float4*)W)[idx];
        m = fmaxf(m, fmaxf(fmaxf(fabsf(v.x), fabsf(v.y)),
                           fmaxf(fabsf(v.z), fabsf(v.w))));
    }
    for (int idx = i0; idx < nx4; idx += stride) {
        float4 v = ((const float4*)X)[idx];
        ushort4 o;
        o.x = f2bf(v.x); o.y = f2bf(v.y); o.z = f2bf(v.z); o.w = f2bf(v.w);
        ((ushort4*)Xb)[idx] = o;
    }
    #pragma unroll
    for (int off = 32; off > 0; off >>= 1)
        m = fmaxf(m, __shfl_down(m, off));
    if ((threadIdx.x & 63) == 0)
        atomicMax(amax, __float_as_uint(m));  // |w| >= 0: uint bits monotone
}

// ---------------- quantize W -> bf16 ---------------------------------------
__global__ void quantize_kernel(const float* __restrict__ W,
                                const unsigned* __restrict__ amax,
                                unsigned short* __restrict__ Wq, int n4) {
    const float scale = __uint_as_float(*amax) / 127.0f;
    int i0 = blockIdx.x * blockDim.x + threadIdx.x;
    int stride = gridDim.x * blockDim.x;
    for (int idx = i0; idx < n4; idx += stride) {
        float4 w = ((const float4*)W)[idx];
        float q0 = fminf(fmaxf(rintf(w.x / scale), -127.f), 127.f) * scale;
        float q1 = fminf(fmaxf(rintf(w.y / scale), -127.f), 127.f) * scale;
        float q2 = fminf(fmaxf(rintf(w.z / scale), -127.f), 127.f) * scale;
        float q3 = fminf(fmaxf(rintf(w.w / scale), -127.f), 127.f) * scale;
        ushort4 o;
        o.x = f2bf(q0); o.y = f2bf(q1); o.z = f2bf(q2); o.w = f2bf(q3);
        ((ushort4*)Wq)[idx] = o;
    }
}

// ---------------- bf16 NT GEMM: C[M,N] = A[M,K] * B[N,K]^T + bias ----------
// Block = 256 threads = 4 waves (2x2), each wave a 64x64 tile as 4x4
// mfma_f32_16x16x32_bf16. Staging lane-permuted: lane i fetches global chunk
// (row = i&15, kquad = i>>4) of its 16-row group, so LDS chunk at 16*i IS the
// MFMA fragment chunk for lane i -> ds_read_b128 at base+16*lane (conflict-
// free contiguous 1 KiB per wave). global_load_lds dest = base + lane*16 (HW).
typedef __attribute__((address_space(3))) void lds_void;
typedef __attribute__((address_space(1))) void gbl_void;

__global__ __launch_bounds__(256) void gemm_bt(
    const unsigned short* __restrict__ A,   // [M,K] bf16 bits
    const unsigned short* __restrict__ B,   // [N,K] bf16 bits
    const float* __restrict__ bias,         // [N]
    float* __restrict__ C, int M, int N, int K)
{
    __shared__ __align__(16) unsigned short sA[BM * BK];  // 8 KiB
    __shared__ __align__(16) unsigned short sB[BN * BK];  // 8 KiB

    const int tid  = threadIdx.x;
    const int wave = tid >> 6;
    const int lane = tid & 63;

    const int rowBase = blockIdx.y * BM;   // M tile
    const int colBase = blockIdx.x * BN;   // N tile

    const int wr = wave >> 1;              // 0..1 : wave row in 2x2
    const int wc = wave & 1;               // 0..1 : wave col

    f32x4 acc[4][4];
    #pragma unroll
    for (int i = 0; i < 4; ++i)
        #pragma unroll
        for (int j = 0; j < 4; ++j)
            acc[i][j] = (f32x4){0.f, 0.f, 0.f, 0.f};

    // lane-permuted staging: lane i covers (row i&15, k-chunk i>>4) of a
    // 16-row x 32-col group -> LDS lands in MFMA fragment order.
    const int lrow = lane & 15;            // 0..15
    const int lcol = (lane >> 4) * 8;      // 0,8,16,24 (elements)

    const int kIters = K / BK;
    for (int kk = 0; kk < kIters; ++kk) {
        const int k0 = kk * BK;
        #pragma unroll
        for (int j = 0; j < 2; ++j) {
            const int g = j * 4 + wave;    // 16-row group 0..7
            const unsigned short* ga =
                A + (size_t)(rowBase + g * 16 + lrow) * K + (k0 + lcol);
            __builtin_amdgcn_global_load_lds((gbl_void*)ga,
                (lds_void*)&sA[g * (16 * BK)], 16, 0, 0);
        }
        #pragma unroll
        for (int j = 0; j < 2; ++j) {
            const int g = j * 4 + wave;
            const unsigned short* gb =
                B + (size_t)(colBase + g * 16 + lrow) * K + (k0 + lcol);
            __builtin_amdgcn_global_load_lds((gbl_void*)gb,
                (lds_void*)&sB[g * (16 * BK)], 16, 0, 0);
        }
        __syncthreads();   // drains vmcnt (global_load_lds) + lgkmcnt

        // fragment loads: contiguous base + 16*lane, conflict-free
        short8 afrag[4], bfrag[4];
        #pragma unroll
        for (int mt = 0; mt < 4; ++mt)
            afrag[mt] = *(const short8*)&sA[(wr * 4 + mt) * (16 * BK) + lane * 8];
        #pragma unroll
        for (int nt = 0; nt < 4; ++nt)
            bfrag[nt] = *(const short8*)&sB[(wc * 4 + nt) * (16 * BK) + lane * 8];

        #pragma unroll
        for (int mt = 0; mt < 4; ++mt)
            #pragma unroll
            for (int nt = 0; nt < 4; ++nt)
                acc[mt][nt] = __builtin_amdgcn_mfma_f32_16x16x32_bf16(
                    afrag[mt], bfrag[nt], acc[mt][nt], 0, 0, 0);

        __syncthreads();   // protect LDS from next iteration's staging
    }

    // epilogue: C/D layout col=lane&15, row=(lane>>4)*4+reg
    const int fr   = lane & 15;
    const int quad = lane >> 4;
    #pragma unroll
    for (int nt = 0; nt < 4; ++nt) {
        const int col = colBase + wc * 64 + nt * 16 + fr;
        const float bv = bias[col];
        #pragma unroll
        for (int mt = 0; mt < 4; ++mt) {
            const int row0 = rowBase + wr * 64 + mt * 16 + quad * 4;
            #pragma unroll
            for (int r = 0; r < 4; ++r)
                C[(size_t)(row0 + r) * N + col] = acc[mt][nt][r] + bv;
        }
    }
}

// ---------------------------------------------------------------------------
extern "C" void kernel_launch(void* const* d_in, const int* in_sizes, int n_in,
                              void* d_out, int out_size, void* d_ws, size_t ws_size,
                              hipStream_t stream) {
    const float* x = (const float*)d_in[0];   // [M,K]
    const float* W = (const float*)d_in[1];   // [N,K]
    const float* b = (const float*)d_in[2];   // [N]
    float* out = (float*)d_out;               // [M,N]

    const int N = in_sizes[2];                // 4096
    const int K = in_sizes[1] / N;            // 4096
    const int M = in_sizes[0] / K;            // 8192

    unsigned char* ws = (unsigned char*)d_ws;
    unsigned* amax = (unsigned*)ws;
    unsigned short* xb = (unsigned short*)(ws + 256);
    unsigned short* wq = (unsigned short*)(ws + 256 + (size_t)M * K * 2);

    hipMemsetAsync(amax, 0, 4, stream);       // ws is re-poisoned every call

    prep_kernel<<<4096, 256, 0, stream>>>(W, x, xb, amax, (N * K) / 4, (M * K) / 4);
    quantize_kernel<<<2048, 256, 0, stream>>>(W, amax, wq, (N * K) / 4);

    dim3 grid(N / BN, M / BM);                // (32, 64)
    gemm_bt<<<grid, 256, 0, stream>>>(xb, wq, b, out, M, N, K);
}

// Round 3
// 709.983 us; speedup vs baseline: 1.3263x; 1.3263x over previous
//
#include <hip/hip_runtime.h>
#include <hip/hip_bf16.h>
#include <stdint.h>

// ---------------------------------------------------------------------------
// Int8Linear: y = x @ Wq^T + b, Wq = dequant(int8-quant(W)) per-tensor absmax.
// R3: XOR-swizzled staging -- lane i stages global chunk
//     (row=i>>2, colchunk=(i&3)^((i>>3)&3)): quads still cover whole 64B
//     lines (R1 coalescing), while the resulting LDS layout makes the
//     ds_read_b128 fragment loads hit all 32 banks per 8-lane phase
//     (R2's zero conflicts). Best of both.
// Workspace: [0..4) absmax bits | 256 + x_bf16 (64 MiB) | wq_bf16 (32 MiB)
// ---------------------------------------------------------------------------

typedef __attribute__((ext_vector_type(8))) short short8;   // 8 x bf16 (4 VGPRs)
typedef __attribute__((ext_vector_type(4))) float f32x4;    // MFMA accumulator

#define BM 128
#define BN 128
#define BK 32

// float -> bf16, round-to-nearest-even
__device__ __forceinline__ unsigned short f2bf(float f) {
    unsigned u = __float_as_uint(f);
    unsigned r = 0x7fffu + ((u >> 16) & 1u);
    return (unsigned short)((u + r) >> 16);
}

// ---------------- absmax over W --------------------------------------------
__global__ void absmax_kernel(const float* __restrict__ W,
                              unsigned* __restrict__ amax, int n4) {
    int i0 = blockIdx.x * blockDim.x + threadIdx.x;
    int stride = gridDim.x * blockDim.x;
    float m = 0.f;
    for (int idx = i0; idx < n4; idx += stride) {
        float4 v = ((const float4*)W)[idx];
        m = fmaxf(m, fmaxf(fmaxf(fabsf(v.x), fabsf(v.y)),
                           fmaxf(fabsf(v.z), fabsf(v.w))));
    }
    #pragma unroll
    for (int off = 32; off > 0; off >>= 1)
        m = fmaxf(m, __shfl_down(m, off));
    if ((threadIdx.x & 63) == 0)
        atomicMax(amax, __float_as_uint(m));  // |w| >= 0: uint bits monotone
}

// ---------------- fused: quantize W -> bf16, cast x -> bf16 ----------------
__global__ void quantcast_kernel(const float* __restrict__ W,
                                 const float* __restrict__ X,
                                 const unsigned* __restrict__ amax,
                                 unsigned short* __restrict__ Wq,
                                 unsigned short* __restrict__ Xb,
                                 int nw4, int nx4) {
    const float scale = __uint_as_float(*amax) / 127.0f;
    const float inv_scale = 127.0f / __uint_as_float(*amax);
    int i0 = blockIdx.x * blockDim.x + threadIdx.x;
    int stride = gridDim.x * blockDim.x;
    for (int idx = i0; idx < nw4; idx += stride) {
        float4 w = ((const float4*)W)[idx];
        float q0 = fminf(fmaxf(rintf(w.x * inv_scale), -127.f), 127.f) * scale;
        float q1 = fminf(fmaxf(rintf(w.y * inv_scale), -127.f), 127.f) * scale;
        float q2 = fminf(fmaxf(rintf(w.z * inv_scale), -127.f), 127.f) * scale;
        float q3 = fminf(fmaxf(rintf(w.w * inv_scale), -127.f), 127.f) * scale;
        ushort4 o;
        o.x = f2bf(q0); o.y = f2bf(q1); o.z = f2bf(q2); o.w = f2bf(q3);
        ((ushort4*)Wq)[idx] = o;
    }
    for (int idx = i0; idx < nx4; idx += stride) {
        float4 v = ((const float4*)X)[idx];
        ushort4 o;
        o.x = f2bf(v.x); o.y = f2bf(v.y); o.z = f2bf(v.z); o.w = f2bf(v.w);
        ((ushort4*)Xb)[idx] = o;
    }
}

// ---------------- bf16 NT GEMM: C[M,N] = A[M,K] * B[N,K]^T + bias ----------
// Block = 256 threads = 4 waves (2x2), each wave a 64x64 tile as 4x4
// mfma_f32_16x16x32_bf16.
// Staging swizzle: lane i stages (row=i>>2, colchunk=(i&3)^((i>>3)&3)) of a
// 16x32 group; quad -> one 64B line (full coalescing). LDS chunk i holds that
// content, so content (r,c) lives at chunk 4r + (c^((r>>1)&3)).
// Fragment read: lane l wants (r=l&15, c=l>>4) -> chunk 4(l&15)+((l>>4)^((l>>1)&3));
// per-8-lane bank-group starts {0,16,4,20,8,24,12,28} -> conflict-free.
typedef __attribute__((address_space(3))) void lds_void;
typedef __attribute__((address_space(1))) void gbl_void;

__global__ __launch_bounds__(256) void gemm_bt(
    const unsigned short* __restrict__ A,   // [M,K] bf16 bits
    const unsigned short* __restrict__ B,   // [N,K] bf16 bits
    const float* __restrict__ bias,         // [N]
    float* __restrict__ C, int M, int N, int K)
{
    __shared__ __align__(16) unsigned short sA[BM * BK];  // 8 KiB
    __shared__ __align__(16) unsigned short sB[BN * BK];  // 8 KiB

    const int tid  = threadIdx.x;
    const int wave = tid >> 6;
    const int lane = tid & 63;

    const int rowBase = blockIdx.y * BM;   // M tile
    const int colBase = blockIdx.x * BN;   // N tile

    const int wr = wave >> 1;              // 0..1 : wave row in 2x2
    const int wc = wave & 1;               // 0..1 : wave col

    f32x4 acc[4][4];
    #pragma unroll
    for (int i = 0; i < 4; ++i)
        #pragma unroll
        for (int j = 0; j < 4; ++j)
            acc[i][j] = (f32x4){0.f, 0.f, 0.f, 0.f};

    // staging swizzle (see header comment)
    const int lrow = lane >> 2;                           // 0..15
    const int lcol = (((lane & 3) ^ ((lane >> 3) & 3))) * 8;  // element col

    // fragment-read LDS chunk index for this lane (within a 16x32 group)
    const int fidx = 4 * (lane & 15) + (((lane >> 4) ^ ((lane >> 1)) & 3) & 3);

    const int kIters = K / BK;
    for (int kk = 0; kk < kIters; ++kk) {
        const int k0 = kk * BK;
        #pragma unroll
        for (int j = 0; j < 2; ++j) {
            const int g = j * 4 + wave;    // 16-row group 0..7
            const unsigned short* ga =
                A + (size_t)(rowBase + g * 16 + lrow) * K + (k0 + lcol);
            __builtin_amdgcn_global_load_lds((gbl_void*)ga,
                (lds_void*)&sA[g * (16 * BK)], 16, 0, 0);
        }
        #pragma unroll
        for (int j = 0; j < 2; ++j) {
            const int g = j * 4 + wave;
            const unsigned short* gb =
                B + (size_t)(colBase + g * 16 + lrow) * K + (k0 + lcol);
            __builtin_amdgcn_global_load_lds((gbl_void*)gb,
                (lds_void*)&sB[g * (16 * BK)], 16, 0, 0);
        }
        __syncthreads();   // drains vmcnt (global_load_lds) + lgkmcnt

        short8 afrag[4], bfrag[4];
        #pragma unroll
        for (int mt = 0; mt < 4; ++mt)
            afrag[mt] = *(const short8*)&sA[(wr * 4 + mt) * (16 * BK) + fidx * 8];
        #pragma unroll
        for (int nt = 0; nt < 4; ++nt)
            bfrag[nt] = *(const short8*)&sB[(wc * 4 + nt) * (16 * BK) + fidx * 8];

        #pragma unroll
        for (int mt = 0; mt < 4; ++mt)
            #pragma unroll
            for (int nt = 0; nt < 4; ++nt)
                acc[mt][nt] = __builtin_amdgcn_mfma_f32_16x16x32_bf16(
                    afrag[mt], bfrag[nt], acc[mt][nt], 0, 0, 0);

        __syncthreads();   // protect LDS from next iteration's staging
    }

    // epilogue: C/D layout col=lane&15, row=(lane>>4)*4+reg
    const int fr   = lane & 15;
    const int quad = lane >> 4;
    #pragma unroll
    for (int nt = 0; nt < 4; ++nt) {
        const int col = colBase + wc * 64 + nt * 16 + fr;
        const float bv = bias[col];
        #pragma unroll
        for (int mt = 0; mt < 4; ++mt) {
            const int row0 = rowBase + wr * 64 + mt * 16 + quad * 4;
            #pragma unroll
            for (int r = 0; r < 4; ++r)
                C[(size_t)(row0 + r) * N + col] = acc[mt][nt][r] + bv;
        }
    }
}

// ---------------------------------------------------------------------------
extern "C" void kernel_launch(void* const* d_in, const int* in_sizes, int n_in,
                              void* d_out, int out_size, void* d_ws, size_t ws_size,
                              hipStream_t stream) {
    const float* x = (const float*)d_in[0];   // [M,K]
    const float* W = (const float*)d_in[1];   // [N,K]
    const float* b = (const float*)d_in[2];   // [N]
    float* out = (float*)d_out;               // [M,N]

    const int N = in_sizes[2];                // 4096
    const int K = in_sizes[1] / N;            // 4096
    const int M = in_sizes[0] / K;            // 8192

    unsigned char* ws = (unsigned char*)d_ws;
    unsigned* amax = (unsigned*)ws;
    unsigned short* xb = (unsigned short*)(ws + 256);
    unsigned short* wq = (unsigned short*)(ws + 256 + (size_t)M * K * 2);

    hipMemsetAsync(amax, 0, 4, stream);       // ws is re-poisoned every call

    absmax_kernel<<<2048, 256, 0, stream>>>(W, amax, (N * K) / 4);
    quantcast_kernel<<<8192, 256, 0, stream>>>(W, x, amax, wq, xb,
                                               (N * K) / 4, (M * K) / 4);

    dim3 grid(N / BN, M / BM);                // (32, 64)
    gemm_bt<<<grid, 256, 0, stream>>>(xb, wq, b, out, M, N, K);
}

// Round 4
// 646.047 us; speedup vs baseline: 1.4576x; 1.0990x over previous
//
#include <hip/hip_runtime.h>
#include <hip/hip_bf16.h>
#include <stdint.h>

// ---------------------------------------------------------------------------
// Int8Linear: y = x @ Wq^T + b, Wq = dequant(int8-quant(W)) per-tensor absmax.
// R4: (a) GEMM switches to mfma_f32_32x32x16_bf16 (higher ceiling: 2382 vs
//     2075 TF, half the MFMA instruction count) with the same XOR-swizzled
//     conflict-free + coalesced staging. (b) Pre-pass: per-block partial-max
//     array (no atomic init -> memset node dropped); 3 graph nodes total.
// Workspace: [0..2KB) partial maxima | 4096 + x_bf16 (64MiB) | wq_bf16 (32MiB)
// ---------------------------------------------------------------------------

typedef __attribute__((ext_vector_type(8))) short short8;    // 8 x bf16
typedef __attribute__((ext_vector_type(16))) float f32x16;   // 32x32 acc

#define BM 128
#define BN 128
#define BK 32
#define PMAX_BLOCKS 512

// float -> bf16, round-to-nearest-even
__device__ __forceinline__ unsigned short f2bf(float f) {
    unsigned u = __float_as_uint(f);
    unsigned r = 0x7fffu + ((u >> 16) & 1u);
    return (unsigned short)((u + r) >> 16);
}

// ---------------- per-block partial absmax over W --------------------------
__global__ void partial_max_kernel(const float* __restrict__ W,
                                   float* __restrict__ partials, int n4) {
    int i0 = blockIdx.x * blockDim.x + threadIdx.x;
    int stride = gridDim.x * blockDim.x;
    float m = 0.f;
    for (int idx = i0; idx < n4; idx += stride) {
        float4 v = ((const float4*)W)[idx];
        m = fmaxf(m, fmaxf(fmaxf(fabsf(v.x), fabsf(v.y)),
                           fmaxf(fabsf(v.z), fabsf(v.w))));
    }
    #pragma unroll
    for (int off = 32; off > 0; off >>= 1)
        m = fmaxf(m, __shfl_down(m, off));
    __shared__ float wmax[4];
    if ((threadIdx.x & 63) == 0) wmax[threadIdx.x >> 6] = m;
    __syncthreads();
    if (threadIdx.x == 0)
        partials[blockIdx.x] = fmaxf(fmaxf(wmax[0], wmax[1]),
                                     fmaxf(wmax[2], wmax[3]));
}

// ---------------- fused: reduce partials, quantize W, cast x ---------------
__global__ void quantcast_kernel(const float* __restrict__ W,
                                 const float* __restrict__ X,
                                 const float* __restrict__ partials,
                                 unsigned short* __restrict__ Wq,
                                 unsigned short* __restrict__ Xb,
                                 int nw4, int nx4) {
    // every block redundantly reduces the 512 partials (2 KB, L2-hot)
    float m = fmaxf(partials[threadIdx.x], partials[threadIdx.x + 256]);
    #pragma unroll
    for (int off = 32; off > 0; off >>= 1)
        m = fmaxf(m, __shfl_down(m, off));
    __shared__ float smax[4];
    if ((threadIdx.x & 63) == 0) smax[threadIdx.x >> 6] = m;
    __syncthreads();
    const float amax = fmaxf(fmaxf(smax[0], smax[1]), fmaxf(smax[2], smax[3]));
    const float scale = amax / 127.0f;
    const float inv_scale = 127.0f / amax;

    int i0 = blockIdx.x * blockDim.x + threadIdx.x;
    int stride = gridDim.x * blockDim.x;
    for (int idx = i0; idx < nw4; idx += stride) {
        float4 w = ((const float4*)W)[idx];
        float q0 = fminf(fmaxf(rintf(w.x * inv_scale), -127.f), 127.f) * scale;
        float q1 = fminf(fmaxf(rintf(w.y * inv_scale), -127.f), 127.f) * scale;
        float q2 = fminf(fmaxf(rintf(w.z * inv_scale), -127.f), 127.f) * scale;
        float q3 = fminf(fmaxf(rintf(w.w * inv_scale), -127.f), 127.f) * scale;
        ushort4 o;
        o.x = f2bf(q0); o.y = f2bf(q1); o.z = f2bf(q2); o.w = f2bf(q3);
        ((ushort4*)Wq)[idx] = o;
    }
    for (int idx = i0; idx < nx4; idx += stride) {
        float4 v = ((const float4*)X)[idx];
        ushort4 o;
        o.x = f2bf(v.x); o.y = f2bf(v.y); o.z = f2bf(v.z); o.w = f2bf(v.w);
        ((ushort4*)Xb)[idx] = o;
    }
}

// ---------------- bf16 NT GEMM: C[M,N] = A[M,K] * B[N,K]^T + bias ----------
// Block = 256 threads = 4 waves (2x2), each wave a 64x64 tile as 2x2
// mfma_f32_32x32x16_bf16 over 2 k-steps per BK=32 tile.
// Staging (same as R3): lane i stages (row=i>>2, colchunk=(i&3)^((i>>3)&3))
// of a 16-row slab; quad -> one 64B line (coalesced). Content (R, c) lands at
// element 1024*(R>>5) + 512*((R>>4)&1) + 32*(R&15) + 8*(c ^ (((R>>1))&3)).
// Fragment (32x32x16): lane wants (r=lane&31, kc=(lane>>5)+2*kstep); the
// resulting chunk starts are all-distinct mod 8 per phase -> conflict-free.
typedef __attribute__((address_space(3))) void lds_void;
typedef __attribute__((address_space(1))) void gbl_void;

__global__ __launch_bounds__(256) void gemm_bt(
    const unsigned short* __restrict__ A,   // [M,K] bf16 bits
    const unsigned short* __restrict__ B,   // [N,K] bf16 bits
    const float* __restrict__ bias,         // [N]
    float* __restrict__ C, int M, int N, int K)
{
    __shared__ __align__(16) unsigned short sA[BM * BK];  // 8 KiB
    __shared__ __align__(16) unsigned short sB[BN * BK];  // 8 KiB

    const int tid  = threadIdx.x;
    const int wave = tid >> 6;
    const int lane = tid & 63;

    const int rowBase = blockIdx.y * BM;   // M tile
    const int colBase = blockIdx.x * BN;   // N tile

    const int wr = wave >> 1;              // 0..1 : wave row in 2x2
    const int wc = wave & 1;               // 0..1 : wave col

    f32x16 acc[2][2];
    #pragma unroll
    for (int i = 0; i < 2; ++i)
        #pragma unroll
        for (int j = 0; j < 2; ++j)
            #pragma unroll
            for (int r = 0; r < 16; ++r)
                acc[i][j][r] = 0.f;

    // staging swizzle (see header comment)
    const int lrow = lane >> 2;                              // 0..15
    const int lcol = ((lane & 3) ^ ((lane >> 3) & 3)) * 8;   // element col

    // fragment offsets within a 32-row group (1024 elements)
    const int fr   = lane & 31;            // m (or n) within group
    const int rr   = fr & 15;
    const int half = fr >> 4;
    const int kc0  = lane >> 5;            // 0/1
    const int sw   = (rr >> 1) & 3;
    const int base_off = half * 512 + rr * 32;
    const int off_k0 = base_off + ((kc0 ^ sw) << 3);
    const int off_k1 = base_off + (((kc0 + 2) ^ sw) << 3);

    const int kIters = K / BK;
    for (int kk = 0; kk < kIters; ++kk) {
        const int k0 = kk * BK;
        #pragma unroll
        for (int j = 0; j < 2; ++j) {
            const int g = j * 4 + wave;    // 16-row slab 0..7
            const unsigned short* ga =
                A + (size_t)(rowBase + g * 16 + lrow) * K + (k0 + lcol);
            __builtin_amdgcn_global_load_lds((gbl_void*)ga,
                (lds_void*)&sA[g * 512], 16, 0, 0);
        }
        #pragma unroll
        for (int j = 0; j < 2; ++j) {
            const int g = j * 4 + wave;
            const unsigned short* gb =
                B + (size_t)(colBase + g * 16 + lrow) * K + (k0 + lcol);
            __builtin_amdgcn_global_load_lds((gbl_void*)gb,
                (lds_void*)&sB[g * 512], 16, 0, 0);
        }
        __syncthreads();   // drains vmcnt (global_load_lds) + lgkmcnt

        short8 af[2][2], bf[2][2];         // [tile][kstep]
        #pragma unroll
        for (int mt = 0; mt < 2; ++mt) {
            const int gbase = (wr * 2 + mt) * 1024;
            af[mt][0] = *(const short8*)&sA[gbase + off_k0];
            af[mt][1] = *(const short8*)&sA[gbase + off_k1];
        }
        #pragma unroll
        for (int nt = 0; nt < 2; ++nt) {
            const int gbase = (wc * 2 + nt) * 1024;
            bf[nt][0] = *(const short8*)&sB[gbase + off_k0];
            bf[nt][1] = *(const short8*)&sB[gbase + off_k1];
        }

        #pragma unroll
        for (int ks = 0; ks < 2; ++ks)
            #pragma unroll
            for (int mt = 0; mt < 2; ++mt)
                #pragma unroll
                for (int nt = 0; nt < 2; ++nt)
                    acc[mt][nt] = __builtin_amdgcn_mfma_f32_32x32x16_bf16(
                        af[mt][ks], bf[nt][ks], acc[mt][nt], 0, 0, 0);

        __syncthreads();   // protect LDS from next iteration's staging
    }

    // epilogue: 32x32 C/D layout col=lane&31, row=(reg&3)+8*(reg>>2)+4*(lane>>5)
    const int ecol = lane & 31;
    const int erow = 4 * (lane >> 5);
    #pragma unroll
    for (int nt = 0; nt < 2; ++nt) {
        const int col = colBase + wc * 64 + nt * 32 + ecol;
        const float bv = bias[col];
        #pragma unroll
        for (int mt = 0; mt < 2; ++mt) {
            const int row0 = rowBase + wr * 64 + mt * 32 + erow;
            #pragma unroll
            for (int reg = 0; reg < 16; ++reg) {
                const int row = row0 + (reg & 3) + 8 * (reg >> 2);
                C[(size_t)row * N + col] = acc[mt][nt][reg] + bv;
            }
        }
    }
}

// ---------------------------------------------------------------------------
extern "C" void kernel_launch(void* const* d_in, const int* in_sizes, int n_in,
                              void* d_out, int out_size, void* d_ws, size_t ws_size,
                              hipStream_t stream) {
    const float* x = (const float*)d_in[0];   // [M,K]
    const float* W = (const float*)d_in[1];   // [N,K]
    const float* b = (const float*)d_in[2];   // [N]
    float* out = (float*)d_out;               // [M,N]

    const int N = in_sizes[2];                // 4096
    const int K = in_sizes[1] / N;            // 4096
    const int M = in_sizes[0] / K;            // 8192

    unsigned char* ws = (unsigned char*)d_ws;
    float* partials = (float*)ws;             // PMAX_BLOCKS floats
    unsigned short* xb = (unsigned short*)(ws + 4096);
    unsigned short* wq = (unsigned short*)(ws + 4096 + (size_t)M * K * 2);

    partial_max_kernel<<<PMAX_BLOCKS, 256, 0, stream>>>(W, partials, (N * K) / 4);
    quantcast_kernel<<<8192, 256, 0, stream>>>(W, x, partials, wq, xb,
                                               (N * K) / 4, (M * K) / 4);

    dim3 grid(N / BN, M / BM);                // (32, 64)
    gemm_bt<<<grid, 256, 0, stream>>>(xb, wq, b, out, M, N, K);
}